// Round 1
// baseline (798.389 us; speedup 1.0000x reference)
//
#include <hip/hip_runtime.h>
#include <math.h>

#define BSZ 4
#define CKC 64
#define HWP 1024
#define NMEM 16384
#define CVC 256
#define PT 16      // pixels per block (main kernel)
#define NT 256     // memory entries per tile

// workspace layout (in floats)
#define WS_BQ_OFF   0
#define WS_BQ_SZ    (BSZ * 128 * HWP)
#define WS_BSQ_OFF  (WS_BQ_OFF + WS_BQ_SZ)
#define WS_BSQ_SZ   (BSZ * HWP)
#define WS_PRE_OFF  (WS_BSQ_OFF + WS_BSQ_SZ)
#define WS_PRE_SZ   (BSZ * HWP)
#define WS_VT_OFF   (WS_PRE_OFF + WS_PRE_SZ)
#define WS_VT_SZ    (BSZ * NMEM * CVC)
#define WS_TOTAL_FLOATS (WS_VT_OFF + WS_VT_SZ)

// ---------------------------------------------------------------------------
// Prep: Bq rows 0..63 = 2*qk*qe ("f"), rows 64..127 = -qe ("g");
// bsq[p] = sum_c qe*qk^2 ; prelogit[p] = b + W_lm*lm + W1.lpf + W2.pf - W3.lmv
// grid: BSZ*64 blocks (16 pixels each), 256 threads (16 px x 16 c-groups)
// ---------------------------------------------------------------------------
__global__ __launch_bounds__(256) void prep_kernel(
    const float* __restrict__ qk, const float* __restrict__ qe,
    const float* __restrict__ pf, const float* __restrict__ lm,
    const float* __restrict__ lpf, const float* __restrict__ lmv,
    const float* __restrict__ W, const float* __restrict__ bu,
    float* __restrict__ Bq, float* __restrict__ bsq, float* __restrict__ prelog)
{
    __shared__ float red[16][17];
    const int t  = threadIdx.x;
    const int b  = blockIdx.x >> 6;
    const int p0 = (blockIdx.x & 63) << 4;
    const int pp = t & 15;
    const int cg = t >> 4;
    const int p  = p0 + pp;

    const float* qkb = qk + (size_t)b * CKC * HWP;
    const float* qeb = qe + (size_t)b * CKC * HWP;
    float* Bqb = Bq + (size_t)b * 128 * HWP;

    float bs = 0.f;
    #pragma unroll
    for (int i = 0; i < 4; ++i) {
        const int cidx = (cg << 2) + i;
        const float k_ = qkb[cidx * HWP + p];
        const float e_ = qeb[cidx * HWP + p];
        Bqb[cidx * HWP + p]        = 2.f * k_ * e_;
        Bqb[(64 + cidx) * HWP + p] = -e_;
        bs += e_ * k_ * k_;
    }
    red[cg][pp] = bs;
    __syncthreads();
    if (t < 16) {
        float s = 0.f;
        #pragma unroll
        for (int g2 = 0; g2 < 16; ++g2) s += red[g2][t];
        bsq[b * HWP + p0 + t] = s;
    }
    const float* lpfb = lpf + (size_t)b * CVC * HWP;
    const float* pfb  = pf  + (size_t)b * CVC * HWP;
    const float* lmvb = lmv + (size_t)b * CVC * HWP;
    float lg = 0.f;
    #pragma unroll
    for (int i = 0; i < 16; ++i) {
        const int cidx = (cg << 4) + i;
        lg += W[cidx]       * lpfb[cidx * HWP + p];
        lg += W[256 + cidx] * pfb[cidx * HWP + p];
        lg -= W[513 + cidx] * lmvb[cidx * HWP + p];
    }
    __syncthreads();
    red[cg][pp] = lg;
    __syncthreads();
    if (t < 16) {
        float s = bu[0] + W[512] * lm[b * HWP + p0 + t];
        #pragma unroll
        for (int g2 = 0; g2 < 16; ++g2) s += red[g2][t];
        prelog[b * HWP + p0 + t] = s;
    }
}

// ---------------------------------------------------------------------------
// Transpose mem_msk_value [b][c][n] -> VT [b][n][c] (coalesced gather later)
// ---------------------------------------------------------------------------
__global__ __launch_bounds__(256) void transpose_v(const float* __restrict__ V,
                                                   float* __restrict__ VT)
{
    __shared__ float tile[32][33];
    const int b  = blockIdx.z;
    const int n0 = blockIdx.x << 5;
    const int c0 = blockIdx.y << 5;
    const int tx = threadIdx.x, ty = threadIdx.y;  // 32 x 8
    const float* Vb  = V  + (size_t)b * CVC * NMEM;
    float*       VTb = VT + (size_t)b * NMEM * CVC;
    #pragma unroll
    for (int i = 0; i < 32; i += 8)
        tile[ty + i][tx] = Vb[(size_t)(c0 + ty + i) * NMEM + n0 + tx];
    __syncthreads();
    #pragma unroll
    for (int i = 0; i < 32; i += 8)
        VTb[(size_t)(n0 + ty + i) * CVC + c0 + tx] = tile[tx][ty + i];
}

// ---------------------------------------------------------------------------
// Main fused kernel: sim GEMM + streaming top-32 + softmax(top-30) + gather
// + uncertainty-gated blend.  grid = BSZ*64 blocks (16 px), 256 threads.
// Thread tile: 4n x 4p;  tn = t&63 (n-groups), tp = t>>6 (p-groups).
// ---------------------------------------------------------------------------
__global__ __launch_bounds__(256) void main_kernel(
    const float* __restrict__ mk, const float* __restrict__ shr,
    const float* __restrict__ valid, const float* __restrict__ Vv,
    const float* __restrict__ lmv, const float* __restrict__ Bq,
    const float* __restrict__ bsq, const float* __restrict__ prelog,
    const float* __restrict__ W, float* __restrict__ out, int use_vt)
{
    __shared__ float fS[64][16];
    __shared__ float gS[64][16];
    __shared__ float mkS[64][256];
    __shared__ float shrS[NT];
    __shared__ float penS[NT];
    __shared__ float bsqS[PT];
    __shared__ float prelS[PT];
    __shared__ float heapV[PT][32];
    __shared__ int   heapI[PT][32];
    __shared__ float minV[PT];
    __shared__ int   minPos[PT];
    __shared__ float qV[PT][64];
    __shared__ int   qI[PT][64];
    __shared__ int   qCnt[PT];
    __shared__ int   pendAny;
    __shared__ float probS[PT][32];
    __shared__ float partS[4][PT];
    __shared__ float upS[PT];

    const int t  = threadIdx.x;
    const int b  = blockIdx.x >> 6;
    const int p0 = (blockIdx.x & 63) << 4;
    const int tn = t & 63;
    const int tp = t >> 6;

    // resident per-block query data
    const float* Bqb = Bq + (size_t)b * 128 * HWP;
    for (int idx = t; idx < 64 * PT; idx += 256) {
        const int c = idx >> 4, pp = idx & 15;
        fS[c][pp] = Bqb[c * HWP + p0 + pp];
        gS[c][pp] = Bqb[(64 + c) * HWP + p0 + pp];
    }
    if (t < PT) {
        bsqS[t]  = bsq[b * HWP + p0 + t];
        prelS[t] = prelog[b * HWP + p0 + t];
        qCnt[t]  = 0;
    }
    if (t == 0) pendAny = 0;

    const float* mkb  = mk  + (size_t)b * CKC * NMEM;
    const float* shrb = shr + (size_t)b * NMEM;
    const float* vlb  = valid + (size_t)b * NMEM;

    for (int ntile = 0; ntile < NMEM / NT; ++ntile) {
        const int n0 = ntile << 8;
        // ---- stage mk tile + shrinkage/penalty (prev tile fully drained: the
        //      while-loop below always exits through a barrier) ----
        shrS[t] = shrb[n0 + t] * 0.125f;               // includes 1/sqrt(CK)
        penS[t] = (1.f - vlb[n0 + t]) * -60000.f;
        #pragma unroll
        for (int k = 0; k < 16; ++k) {
            const int idx = t + (k << 8);              // 0..4095
            const int row = idx >> 6;                  // 0..63
            const int c4  = (idx & 63) << 2;           // 0..252
            *(float4*)&mkS[row][c4] =
                *(const float4*)&mkb[(size_t)row * NMEM + n0 + c4];
        }
        __syncthreads();

        // ---- sim GEMM: acc[i][j] over 64 channels ----
        float acc[4][4];
        #pragma unroll
        for (int i = 0; i < 4; ++i)
            #pragma unroll
            for (int j = 0; j < 4; ++j) acc[i][j] = 0.f;

        #pragma unroll 8
        for (int cc = 0; cc < 64; ++cc) {
            const float4 a4 = *(const float4*)&mkS[cc][tn << 2];
            const float4 f4 = *(const float4*)&fS[cc][tp << 2];
            const float4 g4 = *(const float4*)&gS[cc][tp << 2];
            const float m[4]  = {a4.x, a4.y, a4.z, a4.w};
            const float ff[4] = {f4.x, f4.y, f4.z, f4.w};
            const float gg[4] = {g4.x, g4.y, g4.z, g4.w};
            #pragma unroll
            for (int i = 0; i < 4; ++i) {
                const float mv = m[i];
                const float m2 = mv * mv;
                #pragma unroll
                for (int j = 0; j < 4; ++j)
                    acc[i][j] = fmaf(mv, ff[j], fmaf(m2, gg[j], acc[i][j]));
            }
        }

        float simv[4][4];
        #pragma unroll
        for (int i = 0; i < 4; ++i) {
            const float sh = shrS[(tn << 2) + i];
            const float pe = penS[(tn << 2) + i];
            #pragma unroll
            for (int j = 0; j < 4; ++j)
                simv[i][j] = fmaf(acc[i][j] - bsqS[(tp << 2) + j], sh, pe);
        }

        // ---- streaming top-32 ----
        unsigned pending = 0xFFFFu;
        if (ntile == 0) {
            // warm-up: n = 0..31 fill all 32 heap slots directly
            if (tn < 8) {
                #pragma unroll
                for (int i = 0; i < 4; ++i)
                    #pragma unroll
                    for (int j = 0; j < 4; ++j) {
                        heapV[(tp << 2) + j][(tn << 2) + i] = simv[i][j];
                        heapI[(tp << 2) + j][(tn << 2) + i] = (tn << 2) + i;
                    }
                pending = 0;
            }
            __syncthreads();
            if (t < PT) {
                float mv = heapV[t][0]; int mp = 0;
                #pragma unroll
                for (int s = 1; s < 32; ++s) {
                    const float v = heapV[t][s];
                    if (v < mv) { mv = v; mp = s; }
                }
                minV[t] = mv; minPos[t] = mp;
            }
            __syncthreads();
        }

        while (true) {
            if (t == 0) pendAny = 0;
            if (t < PT) qCnt[t] = 0;
            __syncthreads();
            // filter: push candidates beating current per-pixel min
            if (pending) {
                #pragma unroll
                for (int j = 0; j < 4; ++j) {
                    const int p = (tp << 2) + j;
                    const float mv = minV[p];
                    #pragma unroll
                    for (int i = 0; i < 4; ++i) {
                        const unsigned bitm = 1u << ((j << 2) + i);
                        if (pending & bitm) {
                            const float v = simv[i][j];
                            if (v > mv) {
                                const int slot = atomicAdd(&qCnt[p], 1);
                                if (slot < 64) {
                                    qV[p][slot] = v;
                                    qI[p][slot] = n0 + (tn << 2) + i;
                                    pending &= ~bitm;
                                } // else: queue full, retry next pass
                            } else pending &= ~bitm;   // min only rises: final
                        }
                    }
                }
                if (pending) pendAny = 1;
            }
            __syncthreads();
            // drain: one thread per pixel, replace-min with exact re-check
            if (t < PT) {
                const int p = t;
                int cnt = qCnt[p]; if (cnt > 64) cnt = 64;
                if (cnt) {
                    float mv = minV[p]; int mp = minPos[p];
                    for (int s = 0; s < cnt; ++s) {
                        const float v = qV[p][s];
                        if (v > mv) {
                            heapV[p][mp] = v;
                            heapI[p][mp] = qI[p][s];
                            mv = heapV[p][0]; mp = 0;
                            for (int s2 = 1; s2 < 32; ++s2) {
                                const float v2 = heapV[p][s2];
                                if (v2 < mv) { mv = v2; mp = s2; }
                            }
                        }
                    }
                    minV[p] = mv; minPos[p] = mp;
                }
            }
            __syncthreads();
            const int again = pendAny;
            __syncthreads();
            if (!again) break;
        }
    }

    // ---- softmax over top-30 (exclude 2 smallest of the 32 kept) ----
    if (t < PT) {
        const int p = t;
        float mx = heapV[p][0];
        #pragma unroll
        for (int s = 1; s < 32; ++s) mx = fmaxf(mx, heapV[p][s]);
        float m1v = heapV[p][0]; int m1 = 0;
        #pragma unroll
        for (int s = 1; s < 32; ++s) { const float v = heapV[p][s]; if (v < m1v) { m1v = v; m1 = s; } }
        float m2v = 3.0e38f; int m2 = -1;
        #pragma unroll
        for (int s = 0; s < 32; ++s) {
            if (s != m1) { const float v = heapV[p][s]; if (v < m2v) { m2v = v; m2 = s; } }
        }
        float sum = 0.f;
        #pragma unroll
        for (int s = 0; s < 32; ++s) {
            const float e = (s == m1 || s == m2) ? 0.f : expf(heapV[p][s] - mx);
            probS[p][s] = e; sum += e;
        }
        const float inv = 1.f / sum;
        #pragma unroll
        for (int s = 0; s < 32; ++s) probS[p][s] *= inv;
    }
    __syncthreads();

    // ---- gather visual (t = channel), logit reduce, blend, store ----
    const int c = t;
    float vis[PT];
    const float* Vb = Vv + (use_vt ? (size_t)b * NMEM * CVC : (size_t)b * CVC * NMEM);
    #pragma unroll
    for (int p = 0; p < PT; ++p) {
        float a = 0.f;
        for (int s = 0; s < 32; ++s) {
            const float pr = probS[p][s];          // wave-uniform
            if (pr != 0.f) {
                const int idx = heapI[p][s];
                const float v = use_vt ? Vb[(size_t)idx * CVC + c]
                                       : Vb[(size_t)c * NMEM + idx];
                a = fmaf(pr, v, a);
            }
        }
        vis[p] = a;
    }
    const float w3 = W[513 + c];
    #pragma unroll
    for (int p = 0; p < PT; ++p) {
        float v = w3 * vis[p];
        #pragma unroll
        for (int off = 32; off > 0; off >>= 1) v += __shfl_xor(v, off, 64);
        if (tn == 0) partS[tp][p] = v;
    }
    __syncthreads();
    if (t < PT) {
        const float lg = prelS[t] + partS[0][t] + partS[1][t] + partS[2][t] + partS[3][t];
        upS[t] = 1.f / (1.f + expf(-lg));
    }
    __syncthreads();
    const float* lmvp = lmv + ((size_t)b * CVC + c) * HWP + p0;
    float*       outp = out + ((size_t)b * CVC + c) * HWP + p0;
    #pragma unroll
    for (int p = 0; p < PT; ++p) {
        const float u = upS[p];
        outp[p] = vis[p] * u + lmvp[p] * (1.f - u);
    }
}

// ---------------------------------------------------------------------------
extern "C" void kernel_launch(void* const* d_in, const int* in_sizes, int n_in,
                              void* d_out, int out_size, void* d_ws, size_t ws_size,
                              hipStream_t stream)
{
    const float* qk  = (const float*)d_in[0];
    const float* qe  = (const float*)d_in[1];
    const float* pf  = (const float*)d_in[2];
    // d_in[3] sensory: unused by reference
    const float* lm  = (const float*)d_in[4];
    const float* lpf = (const float*)d_in[5];
    const float* lmv = (const float*)d_in[6];
    const float* mk  = (const float*)d_in[7];
    const float* shr = (const float*)d_in[8];
    const float* Vv  = (const float*)d_in[9];
    const float* vld = (const float*)d_in[10];
    // d_in[11] obj_memory: unused by reference
    const float* W   = (const float*)d_in[12];
    const float* bu  = (const float*)d_in[13];
    float* out = (float*)d_out;
    float* ws  = (float*)d_ws;

    float* Bq     = ws + WS_BQ_OFF;
    float* bsq    = ws + WS_BSQ_OFF;
    float* prelog = ws + WS_PRE_OFF;
    float* VT     = ws + WS_VT_OFF;
    const int use_vt = (ws_size >= (size_t)WS_TOTAL_FLOATS * sizeof(float)) ? 1 : 0;

    prep_kernel<<<BSZ * 64, 256, 0, stream>>>(qk, qe, pf, lm, lpf, lmv, W, bu,
                                              Bq, bsq, prelog);
    if (use_vt)
        transpose_v<<<dim3(NMEM / 32, CVC / 32, BSZ), dim3(32, 8), 0, stream>>>(Vv, VT);
    main_kernel<<<BSZ * 64, 256, 0, stream>>>(mk, shr, vld, use_vt ? VT : Vv,
                                              lmv, Bq, bsq, prelog, W, out, use_vt);
}